// Round 1
// baseline (3046.285 us; speedup 1.0000x reference)
//
#include <hip/hip_runtime.h>

#define DEVI __device__ __forceinline__

static constexpr float BN_INV_F = 0.9999950000374997f; // 1/sqrt(1+1e-5), f32-rounded

// exact (non-contracted) squared distance, matching ((dx^2+dy^2)+dz^2) in f32
DEVI float d2rn(float ax, float ay, float az, float bx, float by, float bz) {
    float dx = __fsub_rn(ax, bx), dy = __fsub_rn(ay, by), dz = __fsub_rn(az, bz);
    return __fadd_rn(__fadd_rn(__fmul_rn(dx, dx), __fmul_rn(dy, dy)), __fmul_rn(dz, dz));
}

DEVI unsigned long long shfl_xor_u64(unsigned long long x, int m) {
    unsigned lo = (unsigned)x, hi = (unsigned)(x >> 32);
    lo = (unsigned)__shfl_xor((int)lo, m, 64);
    hi = (unsigned)__shfl_xor((int)hi, m, 64);
    return ((unsigned long long)hi << 32) | lo;
}

// ---------------- transpose feats [B,N,3] -> [B,3,N] ----------------
__global__ __launch_bounds__(256) void transpose_feats_kernel(
    const float* __restrict__ in, float* __restrict__ outp) {
    const int total = 16 * 3 * 4096;
    int e = blockIdx.x * 256 + threadIdx.x;
    if (e >= total) return;
    int b = e / (3 * 4096);
    int rem = e % (3 * 4096);
    int c = rem / 4096;
    int n = rem % 4096;
    outp[e] = in[((size_t)b * 4096 + n) * 3 + c];
}

// ---------------- furthest point sampling ----------------
// one block per batch; dist chain carried in registers; argmax via packed u64:
// (float_bits(dist) << 32) | (0xFFFFFFFF - idx)  -> max == max dist, ties -> smallest idx
template <int N, int NPOINT>
__global__ __launch_bounds__(256) void fps_kernel(const float* __restrict__ xyz,
                                                  int* __restrict__ fidx) {
    constexpr int PPT = (N + 255) / 256;
    __shared__ float xs[N * 3];
    __shared__ unsigned long long pb[256];
    __shared__ float q[3];
    const int t = threadIdx.x, b = blockIdx.x;
    const float* xb = xyz + (size_t)b * N * 3;
    for (int e = t; e < N * 3; e += 256) xs[e] = xb[e];
    float dist[PPT];
#pragma unroll
    for (int i = 0; i < PPT; ++i) dist[i] = 1e10f;
    if (t == 0) fidx[b * NPOINT] = 0;
    __syncthreads();
    if (t == 0) { q[0] = xs[0]; q[1] = xs[1]; q[2] = xs[2]; }
    __syncthreads();
    for (int it = 1; it < NPOINT; ++it) {
        float qx = q[0], qy = q[1], qz = q[2];
        unsigned long long best = 0ull;
#pragma unroll
        for (int i = 0; i < PPT; ++i) {
            int p = i * 256 + t;
            if (p < N) {
                float d = d2rn(xs[p * 3], xs[p * 3 + 1], xs[p * 3 + 2], qx, qy, qz);
                float nd = fminf(dist[i], d);
                dist[i] = nd;
                unsigned long long pk =
                    ((unsigned long long)__float_as_uint(nd) << 32) |
                    (unsigned)(0xFFFFFFFFu - (unsigned)p);
                if (pk > best) best = pk;
            }
        }
        pb[t] = best;
        __syncthreads();
        if (t < 64) {
            unsigned long long m = pb[t];
            unsigned long long a = pb[t + 64];  if (a > m) m = a;
            a = pb[t + 128]; if (a > m) m = a;
            a = pb[t + 192]; if (a > m) m = a;
            for (int off = 1; off < 64; off <<= 1) {
                unsigned long long o = shfl_xor_u64(m, off);
                if (o > m) m = o;
            }
            if (t == 0) {
                int p = (int)(0xFFFFFFFFu - (unsigned)m);
                q[0] = xs[p * 3]; q[1] = xs[p * 3 + 1]; q[2] = xs[p * 3 + 2];
                fidx[b * NPOINT + it] = p;
            }
        }
        __syncthreads();
    }
}

// ---------------- SA module: ball query + group + MLP(2) + maxpool ----------------
// one block per (b,s) query point. feats layout [B,CIN,N] channel-first.
template <int CIN, int C1, int C2>
__global__ __launch_bounds__(256) void sa_kernel(
    const float* __restrict__ xyz, const float* __restrict__ feats,
    const int* __restrict__ fidx,
    const float* __restrict__ w0, const float* __restrict__ g0, const float* __restrict__ b0,
    const float* __restrict__ w1, const float* __restrict__ g1, const float* __restrict__ b1,
    float* __restrict__ oxyz, float* __restrict__ ofeat,
    int N, int S, float r2) {
    constexpr int NS = 16, C = 3 + CIN;
    __shared__ float h0[NS][C];
    __shared__ float h1[NS][C1];
    __shared__ int ids[NS];
    __shared__ int cnts[256];
    __shared__ float q[3];
    const int t = threadIdx.x;
    const int s = blockIdx.x % S, b = blockIdx.x / S;
    const float* xb = xyz + (size_t)b * N * 3;
    if (t == 0) {
        int qi = fidx[b * S + s];
        float qx = xb[qi * 3], qy = xb[qi * 3 + 1], qz = xb[qi * 3 + 2];
        q[0] = qx; q[1] = qy; q[2] = qz;
        float* op = oxyz + ((size_t)b * S + s) * 3;
        op[0] = qx; op[1] = qy; op[2] = qz;
    }
    __syncthreads();
    const float qx = q[0], qy = q[1], qz = q[2];
    const int chunk = (N + 255) / 256;
    const int lo = t * chunk, hi = min(N, lo + chunk);
    int c0 = 0;
    for (int p = lo; p < hi; ++p)
        if (d2rn(xb[p * 3], xb[p * 3 + 1], xb[p * 3 + 2], qx, qy, qz) < r2) c0++;
    cnts[t] = c0;
    __syncthreads();
    // inclusive Hillis-Steele scan over 256 threads
    for (int off = 1; off < 256; off <<= 1) {
        int add = (t >= off) ? cnts[t - off] : 0;
        __syncthreads();
        cnts[t] += add;
        __syncthreads();
    }
    const int total = cnts[255];
    int rank = cnts[t] - c0;  // exclusive start
    if (rank < NS) {
        for (int p = lo; p < hi && rank < NS; ++p) {
            if (d2rn(xb[p * 3], xb[p * 3 + 1], xb[p * 3 + 2], qx, qy, qz) < r2) {
                ids[rank] = p;
                rank++;
            }
        }
    }
    __syncthreads();
    if (t == 0) {
        int cnt = min(total, NS);   // cnt >= 1 always (query point itself hits)
        for (int r = cnt; r < NS; ++r) ids[r] = ids[0];
    }
    __syncthreads();
    // build grouped features h0[k][c]: [g_xyz(3) | g_feat(CIN)]
    for (int e = t; e < NS * C; e += 256) {
        int k = e / C, c = e % C;
        int p = ids[k];
        float v = (c < 3) ? __fsub_rn(xb[p * 3 + c], q[c])
                          : feats[((size_t)b * CIN + (c - 3)) * N + p];
        h0[k][c] = v;
    }
    __syncthreads();
    // layer 1
    for (int e = t; e < NS * C1; e += 256) {
        int k = e / C1, o = e % C1;
        const float* wr = w0 + (size_t)o * C;
        float acc = 0.f;
        for (int c = 0; c < C; ++c) acc = fmaf(h0[k][c], wr[c], acc);
        h1[k][o] = fmaxf(fmaf(acc, g0[o] * BN_INV_F, b0[o]), 0.f);
    }
    __syncthreads();
    // layer 2 + maxpool over k
    for (int o = t; o < C2; o += 256) {
        const float* wr = w1 + (size_t)o * C1;
        float accs[NS];
#pragma unroll
        for (int k = 0; k < NS; ++k) accs[k] = 0.f;
        for (int c = 0; c < C1; ++c) {
            float wv = wr[c];
#pragma unroll
            for (int k = 0; k < NS; ++k) accs[k] = fmaf(h1[k][c], wv, accs[k]);
        }
        float scale = g1[o] * BN_INV_F, bb = b1[o];
        float m = -1e30f;
#pragma unroll
        for (int k = 0; k < NS; ++k) m = fmaxf(m, fmaxf(fmaf(accs[k], scale, bb), 0.f));
        ofeat[((size_t)b * C2 + o) * S + s] = m;
    }
}

// ---------------- FP module: 3-NN interp + concat + MLP(2) [+ fused final conv] ----------------
// block handles TR consecutive unknown points (TR | NU so no batch crossing).
template <int M, int CK, int CU, int C1, int C2, int TR, bool FINAL>
__global__ __launch_bounds__(256) void fp_kernel(
    const float* __restrict__ uxyz, const float* __restrict__ kxyz,
    const float* __restrict__ ufeat, const float* __restrict__ kfeat,
    const float* __restrict__ w0, const float* __restrict__ g0, const float* __restrict__ b0,
    const float* __restrict__ w1, const float* __restrict__ g1, const float* __restrict__ b1,
    const float* __restrict__ fw, const float* __restrict__ fb,
    const float* __restrict__ fg, const float* __restrict__ fbe,
    float* __restrict__ out, int NU) {
    constexpr int CH = CK + CU;
    __shared__ float Xs[TR][CH];
    __shared__ float Y1[TR][C1];
    __shared__ float Y2[FINAL ? TR * C2 : 1];
    const int t = threadIdx.x, lane = t & 63, wv = t >> 6;
    const int r0 = blockIdx.x * TR;
    const int b = r0 / NU;
    const float* kb = kxyz + (size_t)b * M * 3;
    // phase A: per wave, one unknown point at a time: 3-NN + interp row into LDS
    for (int j = wv; j < TR; j += 4) {
        int r = r0 + j, nu = r % NU;
        const float* up = uxyz + (size_t)r * 3;
        float ux = up[0], uy = up[1], uz = up[2];
        int s0 = -1, s1 = -1, s2 = -1;
        float d0 = 0.f, d1 = 0.f, dd2 = 0.f;
        for (int pass = 0; pass < 3; ++pass) {
            unsigned long long best = ~0ull;  // min of (d2_bits<<32)|idx -> smallest d2, ties->low idx
            for (int k = lane; k < M; k += 64) {
                if (k == s0 || k == s1) continue;
                float d = d2rn(kb[k * 3], kb[k * 3 + 1], kb[k * 3 + 2], ux, uy, uz);
                unsigned long long pk =
                    ((unsigned long long)__float_as_uint(d) << 32) | (unsigned)k;
                if (pk < best) best = pk;
            }
            for (int off = 1; off < 64; off <<= 1) {
                unsigned long long o = shfl_xor_u64(best, off);
                if (o < best) best = o;
            }
            int idx = (int)(unsigned)best;
            float dv = __uint_as_float((unsigned)(best >> 32));
            if (pass == 0) { s0 = idx; d0 = dv; }
            else if (pass == 1) { s1 = idx; d1 = dv; }
            else { s2 = idx; dd2 = dv; }
        }
        float wa = 1.0f / (d0 + 1e-8f), wb = 1.0f / (d1 + 1e-8f), wc = 1.0f / (dd2 + 1e-8f);
        float sum = (wa + wb) + wc;
        wa /= sum; wb /= sum; wc /= sum;
        for (int c = lane; c < CH; c += 64) {
            float v;
            if (c < CK) {
                const float* kf = kfeat + ((size_t)b * CK + c) * M;
                v = kf[s0] * wa + kf[s1] * wb + kf[s2] * wc;
            } else {
                v = ufeat[((size_t)b * CU + (c - CK)) * NU + nu];
            }
            Xs[j][c] = v;
        }
    }
    __syncthreads();
    // layer 1
    for (int e = t; e < TR * C1; e += 256) {
        int j = e / C1, o = e % C1;
        const float* wr = w0 + (size_t)o * CH;
        float acc = 0.f;
        for (int c = 0; c < CH; ++c) acc = fmaf(Xs[j][c], wr[c], acc);
        Y1[j][o] = fmaxf(fmaf(acc, g0[o] * BN_INV_F, b0[o]), 0.f);
    }
    __syncthreads();
    // layer 2
    for (int e = t; e < TR * C2; e += 256) {
        int j = e / C2, o = e % C2;
        const float* wr = w1 + (size_t)o * C1;
        float acc = 0.f;
        for (int c = 0; c < C1; ++c) acc = fmaf(Y1[j][c], wr[c], acc);
        acc = fmaxf(fmaf(acc, g1[o] * BN_INV_F, b1[o]), 0.f);
        if constexpr (FINAL) {
            Y2[j * C2 + o] = acc;
        } else {
            int r = r0 + j, nu = r % NU;
            out[((size_t)b * C2 + o) * NU + nu] = acc;
        }
    }
    if constexpr (FINAL) {
        __syncthreads();
        // final Conv1d(C2->512) + bias + BN + ReLU, write [B*NU, 512]
        for (int e = t; e < TR * 512; e += 256) {
            int j = e / 512, o = e % 512;
            const float* wr = fw + (size_t)o * C2;
            float acc = 0.f;
            for (int c = 0; c < C2; ++c) acc = fmaf(Y2[j * C2 + c], wr[c], acc);
            acc += fb[o];
            acc = fmaxf(fmaf(acc, fg[o] * BN_INV_F, fbe[o]), 0.f);
            out[(size_t)(r0 + j) * 512 + o] = acc;
        }
    }
}

extern "C" void kernel_launch(void* const* d_in, const int* in_sizes, int n_in,
                              void* d_out, int out_size, void* d_ws, size_t ws_size,
                              hipStream_t stream) {
    (void)in_sizes; (void)n_in; (void)out_size; (void)ws_size;
    const float* xyz   = (const float*)d_in[0];
    const float* feats = (const float*)d_in[1];
    const float* sa1_w0 = (const float*)d_in[2];
    const float* sa1_g0 = (const float*)d_in[3];
    const float* sa1_b0 = (const float*)d_in[4];
    const float* sa1_w1 = (const float*)d_in[5];
    const float* sa1_g1 = (const float*)d_in[6];
    const float* sa1_b1 = (const float*)d_in[7];
    const float* sa2_w0 = (const float*)d_in[8];
    const float* sa2_g0 = (const float*)d_in[9];
    const float* sa2_b0 = (const float*)d_in[10];
    const float* sa2_w1 = (const float*)d_in[11];
    const float* sa2_g1 = (const float*)d_in[12];
    const float* sa2_b1 = (const float*)d_in[13];
    const float* sa3_w0 = (const float*)d_in[14];
    const float* sa3_g0 = (const float*)d_in[15];
    const float* sa3_b0 = (const float*)d_in[16];
    const float* sa3_w1 = (const float*)d_in[17];
    const float* sa3_g1 = (const float*)d_in[18];
    const float* sa3_b1 = (const float*)d_in[19];
    const float* fp3_w0 = (const float*)d_in[20];
    const float* fp3_g0 = (const float*)d_in[21];
    const float* fp3_b0 = (const float*)d_in[22];
    const float* fp3_w1 = (const float*)d_in[23];
    const float* fp3_g1 = (const float*)d_in[24];
    const float* fp3_b1 = (const float*)d_in[25];
    const float* fp2_w0 = (const float*)d_in[26];
    const float* fp2_g0 = (const float*)d_in[27];
    const float* fp2_b0 = (const float*)d_in[28];
    const float* fp2_w1 = (const float*)d_in[29];
    const float* fp2_g1 = (const float*)d_in[30];
    const float* fp2_b1 = (const float*)d_in[31];
    const float* fp1_w0 = (const float*)d_in[32];
    const float* fp1_g0 = (const float*)d_in[33];
    const float* fp1_b0 = (const float*)d_in[34];
    const float* fp1_w1 = (const float*)d_in[35];
    const float* fp1_g1 = (const float*)d_in[36];
    const float* fp1_b1 = (const float*)d_in[37];
    const float* fin_w  = (const float*)d_in[38];
    const float* fin_b  = (const float*)d_in[39];
    const float* fin_g  = (const float*)d_in[40];
    const float* fin_be = (const float*)d_in[41];

    float* ws = (float*)d_ws;
    float* f0   = ws;                 // 16*3*4096   = 196608
    float* l1x  = f0 + 196608;        // 16*256*3    = 12288
    float* l1f  = l1x + 12288;        // 16*128*256  = 524288
    float* l2x  = l1f + 524288;       // 16*64*3     = 3072
    float* l2f  = l2x + 3072;         // 16*256*64   = 262144
    float* l3x  = l2f + 262144;       // 16*16*3     = 768
    float* l3f  = l3x + 768;          // 16*512*16   = 131072
    float* l2fb = l3f + 131072;       // 16*256*64   = 262144
    float* l1fb = l2fb + 262144;      // 16*128*256  = 524288
    int* fidx1 = (int*)(l1fb + 524288);  // 16*256
    int* fidx2 = fidx1 + 4096;           // 16*64
    int* fidx3 = fidx2 + 1024;           // 16*16

    const float R2_1 = (float)(0.04 * 0.04);
    const float R2_2 = (float)(0.08 * 0.08);
    const float R2_3 = (float)(0.16 * 0.16);

    transpose_feats_kernel<<<(16 * 3 * 4096 + 255) / 256, 256, 0, stream>>>(feats, f0);

    fps_kernel<4096, 256><<<16, 256, 0, stream>>>(xyz, fidx1);
    sa_kernel<3, 64, 128><<<16 * 256, 256, 0, stream>>>(
        xyz, f0, fidx1, sa1_w0, sa1_g0, sa1_b0, sa1_w1, sa1_g1, sa1_b1,
        l1x, l1f, 4096, 256, R2_1);

    fps_kernel<256, 64><<<16, 256, 0, stream>>>(l1x, fidx2);
    sa_kernel<128, 128, 256><<<16 * 64, 256, 0, stream>>>(
        l1x, l1f, fidx2, sa2_w0, sa2_g0, sa2_b0, sa2_w1, sa2_g1, sa2_b1,
        l2x, l2f, 256, 64, R2_2);

    fps_kernel<64, 16><<<16, 256, 0, stream>>>(l2x, fidx3);
    sa_kernel<256, 256, 512><<<16 * 16, 256, 0, stream>>>(
        l2x, l2f, fidx3, sa3_w0, sa3_g0, sa3_b0, sa3_w1, sa3_g1, sa3_b1,
        l3x, l3f, 64, 16, R2_3);

    // FP3: unk=l2 (NU=64), kn=l3 (M=16), CK=512, CU=256 -> 256
    fp_kernel<16, 512, 256, 256, 256, 8, false><<<16 * 64 / 8, 256, 0, stream>>>(
        l2x, l3x, l2f, l3f, fp3_w0, fp3_g0, fp3_b0, fp3_w1, fp3_g1, fp3_b1,
        nullptr, nullptr, nullptr, nullptr, l2fb, 64);

    // FP2: unk=l1 (NU=256), kn=l2 (M=64), CK=256, CU=128 -> 128
    fp_kernel<64, 256, 128, 128, 128, 16, false><<<16 * 256 / 16, 256, 0, stream>>>(
        l1x, l2x, l1f, l2fb, fp2_w0, fp2_g0, fp2_b0, fp2_w1, fp2_g1, fp2_b1,
        nullptr, nullptr, nullptr, nullptr, l1fb, 256);

    // FP1: unk=xyz (NU=4096), kn=l1 (M=256), CK=128, CU=3 -> 128, fused final 128->512
    fp_kernel<256, 128, 3, 128, 128, 16, true><<<16 * 4096 / 16, 256, 0, stream>>>(
        xyz, l1x, f0, l1fb, fp1_w0, fp1_g0, fp1_b0, fp1_w1, fp1_g1, fp1_b1,
        fin_w, fin_b, fin_g, fin_be, (float*)d_out, 4096);
}

// Round 2
// 1330.277 us; speedup vs baseline: 2.2900x; 2.2900x over previous
//
#include <hip/hip_runtime.h>

#define DEVI __device__ __forceinline__

static constexpr float BN_INV_F = 0.9999950000374997f; // 1/sqrt(1+1e-5), f32-rounded

// exact (non-contracted) squared distance, matching ((dx^2+dy^2)+dz^2) in f32
DEVI float d2rn(float ax, float ay, float az, float bx, float by, float bz) {
    float dx = __fsub_rn(ax, bx), dy = __fsub_rn(ay, by), dz = __fsub_rn(az, bz);
    return __fadd_rn(__fadd_rn(__fmul_rn(dx, dx), __fmul_rn(dy, dy)), __fmul_rn(dz, dz));
}

DEVI unsigned long long shfl_xor_u64(unsigned long long x, int m) {
    unsigned lo = (unsigned)x, hi = (unsigned)(x >> 32);
    lo = (unsigned)__shfl_xor((int)lo, m, 64);
    hi = (unsigned)__shfl_xor((int)hi, m, 64);
    return ((unsigned long long)hi << 32) | lo;
}

// ---------------- furthest point sampling ----------------
template <int N, int NPOINT>
__global__ __launch_bounds__(256) void fps_kernel(const float* __restrict__ xyz,
                                                  int* __restrict__ fidx) {
    constexpr int PPT = (N + 255) / 256;
    __shared__ float xs[N * 3];
    __shared__ unsigned long long pb[256];
    __shared__ float q[3];
    const int t = threadIdx.x, b = blockIdx.x;
    const float* xb = xyz + (size_t)b * N * 3;
    for (int e = t; e < N * 3; e += 256) xs[e] = xb[e];
    float dist[PPT];
#pragma unroll
    for (int i = 0; i < PPT; ++i) dist[i] = 1e10f;
    if (t == 0) fidx[b * NPOINT] = 0;
    __syncthreads();
    if (t == 0) { q[0] = xs[0]; q[1] = xs[1]; q[2] = xs[2]; }
    __syncthreads();
    for (int it = 1; it < NPOINT; ++it) {
        float qx = q[0], qy = q[1], qz = q[2];
        unsigned long long best = 0ull;
#pragma unroll
        for (int i = 0; i < PPT; ++i) {
            int p = i * 256 + t;
            if (p < N) {
                float d = d2rn(xs[p * 3], xs[p * 3 + 1], xs[p * 3 + 2], qx, qy, qz);
                float nd = fminf(dist[i], d);
                dist[i] = nd;
                unsigned long long pk =
                    ((unsigned long long)__float_as_uint(nd) << 32) |
                    (unsigned)(0xFFFFFFFFu - (unsigned)p);
                if (pk > best) best = pk;
            }
        }
        pb[t] = best;
        __syncthreads();
        if (t < 64) {
            unsigned long long m = pb[t];
            unsigned long long a = pb[t + 64];  if (a > m) m = a;
            a = pb[t + 128]; if (a > m) m = a;
            a = pb[t + 192]; if (a > m) m = a;
            for (int off = 1; off < 64; off <<= 1) {
                unsigned long long o = shfl_xor_u64(m, off);
                if (o > m) m = o;
            }
            if (t == 0) {
                int p = (int)(0xFFFFFFFFu - (unsigned)m);
                q[0] = xs[p * 3]; q[1] = xs[p * 3 + 1]; q[2] = xs[p * 3 + 2];
                fidx[b * NPOINT + it] = p;
            }
        }
        __syncthreads();
    }
}

// ---------------- SA module: ball query + group + MLP(2) + maxpool ----------------
// point-major feats [B,N,CIN]; outputs oxyz [B,S,3], ofeat [B,S,C2] (point-major)
template <int CIN, int C1, int C2>
__global__ __launch_bounds__(256) void sa_kernel(
    const float* __restrict__ xyz, const float* __restrict__ feats,
    const int* __restrict__ fidx,
    const float* __restrict__ w0, const float* __restrict__ g0, const float* __restrict__ b0,
    const float* __restrict__ w1, const float* __restrict__ g1, const float* __restrict__ b1,
    float* __restrict__ oxyz, float* __restrict__ ofeat,
    int N, int S, float r2) {
    constexpr int NS = 16, C = 3 + CIN;
    __shared__ float h0[NS][C];
    __shared__ float h1[NS][C1];
    __shared__ int ids[NS];
    __shared__ int wsum[4];
    __shared__ float q[3];
    const int t = threadIdx.x;
    const int s = blockIdx.x % S, b = blockIdx.x / S;
    const float* xb = xyz + (size_t)b * N * 3;
    if (t == 0) {
        int qi = fidx[b * S + s];
        float qx = xb[qi * 3], qy = xb[qi * 3 + 1], qz = xb[qi * 3 + 2];
        q[0] = qx; q[1] = qy; q[2] = qz;
        float* op = oxyz + ((size_t)b * S + s) * 3;
        op[0] = qx; op[1] = qy; op[2] = qz;
    }
    __syncthreads();
    const float qx = q[0], qy = q[1], qz = q[2];
    const int chunk = (N + 255) / 256;
    const int lo = t * chunk, hi = min(N, lo + chunk);
    int c0 = 0;
    for (int p = lo; p < hi; ++p)
        if (d2rn(xb[p * 3], xb[p * 3 + 1], xb[p * 3 + 2], qx, qy, qz) < r2) c0++;
    // wave-level inclusive scan, then cross-wave fixup
    const int lane = t & 63, wv = t >> 6;
    int v = c0;
    for (int off = 1; off < 64; off <<= 1) {
        int n = __shfl_up(v, off, 64);
        if (lane >= off) v += n;
    }
    if (lane == 63) wsum[wv] = v;
    __syncthreads();
    int pre = 0;
    for (int i = 0; i < wv; ++i) pre += wsum[i];
    const int total = wsum[0] + wsum[1] + wsum[2] + wsum[3];
    int rank = pre + v - c0;  // exclusive start
    if (rank < NS && c0 > 0) {
        for (int p = lo; p < hi && rank < NS; ++p) {
            if (d2rn(xb[p * 3], xb[p * 3 + 1], xb[p * 3 + 2], qx, qy, qz) < r2) {
                ids[rank] = p;
                rank++;
            }
        }
    }
    __syncthreads();
    if (t == 0) {
        int cnt = min(total, NS);   // cnt >= 1 (query point itself is a hit)
        for (int r = cnt; r < NS; ++r) ids[r] = ids[0];
    }
    __syncthreads();
    // grouped features h0[k][c] = [g_xyz(3) | g_feat(CIN)], feats point-major
    for (int e = t; e < NS * C; e += 256) {
        int k = e / C, c = e % C;
        int p = ids[k];
        float val = (c < 3) ? __fsub_rn(xb[p * 3 + c], q[c])
                            : feats[((size_t)b * N + p) * CIN + (c - 3)];
        h0[k][c] = val;
    }
    __syncthreads();
    // layer 1
    for (int e = t; e < NS * C1; e += 256) {
        int k = e / C1, o = e % C1;
        const float* wr = w0 + (size_t)o * C;
        float acc = 0.f;
        for (int c = 0; c < C; ++c) acc = fmaf(h0[k][c], wr[c], acc);
        h1[k][o] = fmaxf(fmaf(acc, g0[o] * BN_INV_F, b0[o]), 0.f);
    }
    __syncthreads();
    // layer 2 + maxpool over k; ofeat point-major
    for (int o = t; o < C2; o += 256) {
        const float* wr = w1 + (size_t)o * C1;
        float accs[NS];
#pragma unroll
        for (int k = 0; k < NS; ++k) accs[k] = 0.f;
        for (int c = 0; c < C1; ++c) {
            float wvv = wr[c];
#pragma unroll
            for (int k = 0; k < NS; ++k) accs[k] = fmaf(h1[k][c], wvv, accs[k]);
        }
        float scale = g1[o] * BN_INV_F, bb = b1[o];
        float m = -1e30f;
#pragma unroll
        for (int k = 0; k < NS; ++k) m = fmaxf(m, fmaxf(fmaf(accs[k], scale, bb), 0.f));
        ofeat[((size_t)b * S + s) * C2 + o] = m;
    }
}

// ---------------- register-tiled GEMM phase for FP MLPs ----------------
// 256 threads = 16(ty) x 16(tx). Thread tile: RT rows x 8 cols (cols tx+16i).
// X in LDS [TR][XSTR]; W chunk staged to Ws[128][20]; output overwrites Xs
// (EPI=false, full-phase accumulation in registers) or goes to global (EPI=true).
template <int TR, int XSTR, int CI, int CO, bool FINAL_EPI>
DEVI void gemm_phase(float* Xs, float* Ws,
                     const float* __restrict__ W, const float* __restrict__ g,
                     const float* __restrict__ bt,
                     const float* __restrict__ fb, const float* __restrict__ fg,
                     const float* __restrict__ fbe,
                     float* __restrict__ gout, int r0, int t) {
    constexpr int RT = TR / 16;
    constexpr int CC = CO / 128;
    constexpr int CI16 = ((CI + 15) / 16) * 16;
    const int tx = t & 15, ty = t >> 4;

    if constexpr (!FINAL_EPI) {
        float acc[CC][RT][8];
#pragma unroll
        for (int cc = 0; cc < CC; ++cc)
#pragma unroll
            for (int r = 0; r < RT; ++r)
#pragma unroll
                for (int i = 0; i < 8; ++i) acc[cc][r][i] = 0.f;
        for (int cc = 0; cc < CC; ++cc) {
            for (int k0 = 0; k0 < CI16; k0 += 16) {
                __syncthreads();
                for (int idx = t; idx < 2048; idx += 256) {
                    int row = idx >> 4, kk = idx & 15;
                    int k = k0 + kk;
                    Ws[row * 20 + kk] =
                        (k < CI) ? W[(size_t)(cc * 128 + row) * CI + k] : 0.f;
                }
                __syncthreads();
#pragma unroll
                for (int k4 = 0; k4 < 4; ++k4) {
                    float4 wv[8];
#pragma unroll
                    for (int i = 0; i < 8; ++i)
                        wv[i] = *(const float4*)&Ws[(tx + 16 * i) * 20 + k4 * 4];
#pragma unroll
                    for (int r = 0; r < RT; ++r) {
                        float4 xv = *(const float4*)&Xs[(ty * RT + r) * XSTR + k0 + k4 * 4];
#pragma unroll
                        for (int i = 0; i < 8; ++i) {
                            acc[cc][r][i] = fmaf(xv.x, wv[i].x, acc[cc][r][i]);
                            acc[cc][r][i] = fmaf(xv.y, wv[i].y, acc[cc][r][i]);
                            acc[cc][r][i] = fmaf(xv.z, wv[i].z, acc[cc][r][i]);
                            acc[cc][r][i] = fmaf(xv.w, wv[i].w, acc[cc][r][i]);
                        }
                    }
                }
            }
        }
        __syncthreads();
#pragma unroll
        for (int cc = 0; cc < CC; ++cc)
#pragma unroll
            for (int i = 0; i < 8; ++i) {
                int c = cc * 128 + tx + 16 * i;
                float sc = g[c] * BN_INV_F, bb = bt[c];
#pragma unroll
                for (int r = 0; r < RT; ++r)
                    Xs[(ty * RT + r) * XSTR + c] =
                        fmaxf(fmaf(acc[cc][r][i], sc, bb), 0.f);
            }
        __syncthreads();
    } else {
        for (int cc = 0; cc < CC; ++cc) {
            float acc[RT][8];
#pragma unroll
            for (int r = 0; r < RT; ++r)
#pragma unroll
                for (int i = 0; i < 8; ++i) acc[r][i] = 0.f;
            for (int k0 = 0; k0 < CI16; k0 += 16) {
                __syncthreads();
                for (int idx = t; idx < 2048; idx += 256) {
                    int row = idx >> 4, kk = idx & 15;
                    int k = k0 + kk;
                    Ws[row * 20 + kk] =
                        (k < CI) ? W[(size_t)(cc * 128 + row) * CI + k] : 0.f;
                }
                __syncthreads();
#pragma unroll
                for (int k4 = 0; k4 < 4; ++k4) {
                    float4 wv[8];
#pragma unroll
                    for (int i = 0; i < 8; ++i)
                        wv[i] = *(const float4*)&Ws[(tx + 16 * i) * 20 + k4 * 4];
#pragma unroll
                    for (int r = 0; r < RT; ++r) {
                        float4 xv = *(const float4*)&Xs[(ty * RT + r) * XSTR + k0 + k4 * 4];
#pragma unroll
                        for (int i = 0; i < 8; ++i) {
                            acc[r][i] = fmaf(xv.x, wv[i].x, acc[r][i]);
                            acc[r][i] = fmaf(xv.y, wv[i].y, acc[r][i]);
                            acc[r][i] = fmaf(xv.z, wv[i].z, acc[r][i]);
                            acc[r][i] = fmaf(xv.w, wv[i].w, acc[r][i]);
                        }
                    }
                }
            }
#pragma unroll
            for (int i = 0; i < 8; ++i) {
                int c = cc * 128 + tx + 16 * i;
                float bia = fb[c], sc = fg[c] * BN_INV_F, be = fbe[c];
#pragma unroll
                for (int r = 0; r < RT; ++r) {
                    float val = fmaxf(fmaf(acc[r][i] + bia, sc, be), 0.f);
                    gout[(size_t)(r0 + ty * RT + r) * 512 + c] = val;
                }
            }
        }
    }
}

// ---------------- FP module: 3-NN interp + concat + tiled MLP [+ fused final] ----------------
// all feature tensors point-major. Block handles TR consecutive global rows.
template <int M, int CK, int CU, int C1, int C2, int TR, bool FINAL>
__global__ __launch_bounds__(256) void fp_kernel(
    const float* __restrict__ uxyz, const float* __restrict__ kxyz,
    const float* __restrict__ ufeat, const float* __restrict__ kfeat,
    const float* __restrict__ w0, const float* __restrict__ g0, const float* __restrict__ b0,
    const float* __restrict__ w1, const float* __restrict__ g1, const float* __restrict__ b1,
    const float* __restrict__ fw, const float* __restrict__ fb,
    const float* __restrict__ fg, const float* __restrict__ fbe,
    float* __restrict__ out, int NU) {
    constexpr int CH = CK + CU;
    constexpr int CI16A = ((CH + 15) / 16) * 16;
    constexpr int XSTR = CI16A + ((CI16A % 32 == 0) ? 16 : 0);
    __shared__ __align__(16) float Xs[TR * XSTR];
    __shared__ __align__(16) float Ws[128 * 20];
    __shared__ float kxs[M * 3];
    __shared__ int sidx[TR][3];
    __shared__ float swgt[TR][3];
    const int t = threadIdx.x;
    const int r0 = blockIdx.x * TR;
    const int b = r0 / NU;
    // stage known xyz
    for (int e = t; e < M * 3; e += 256) kxs[e] = kxyz[(size_t)b * M * 3 + e];
    __syncthreads();
    // 3-NN: lane j handles row j (serial stable top-3 scan, exact tie-break)
    if (t < TR) {
        const float* up = uxyz + (size_t)(r0 + t) * 3;
        float ux = up[0], uy = up[1], uz = up[2];
        float d0 = 1e30f, d1 = 1e30f, dd2 = 1e30f;
        int s0 = 0, s1 = 0, s2 = 0;
        for (int k = 0; k < M; ++k) {
            float d = d2rn(kxs[k * 3], kxs[k * 3 + 1], kxs[k * 3 + 2], ux, uy, uz);
            if (d < d0)      { dd2 = d1; s2 = s1; d1 = d0; s1 = s0; d0 = d; s0 = k; }
            else if (d < d1) { dd2 = d1; s2 = s1; d1 = d;  s1 = k; }
            else if (d < dd2){ dd2 = d;  s2 = k; }
        }
        float wa = 1.0f / (d0 + 1e-8f), wb = 1.0f / (d1 + 1e-8f), wc = 1.0f / (dd2 + 1e-8f);
        float sum = (wa + wb) + wc;
        wa /= sum; wb /= sum; wc /= sum;
        sidx[t][0] = s0; sidx[t][1] = s1; sidx[t][2] = s2;
        swgt[t][0] = wa; swgt[t][1] = wb; swgt[t][2] = wc;
    }
    __syncthreads();
    // interp fill (float4 over CK), then unknown feats, then zero-pad
    constexpr int CK4 = CK / 4;
    for (int e = t; e < TR * CK4; e += 256) {
        int j = e / CK4, c4 = e % CK4;
        const float* kb = kfeat + (size_t)b * M * CK;
        float4 a  = *(const float4*)(kb + (size_t)sidx[j][0] * CK + c4 * 4);
        float4 b2 = *(const float4*)(kb + (size_t)sidx[j][1] * CK + c4 * 4);
        float4 c2 = *(const float4*)(kb + (size_t)sidx[j][2] * CK + c4 * 4);
        float wa = swgt[j][0], wb = swgt[j][1], wc = swgt[j][2];
        float4 r;
        r.x = a.x * wa + b2.x * wb + c2.x * wc;
        r.y = a.y * wa + b2.y * wb + c2.y * wc;
        r.z = a.z * wa + b2.z * wb + c2.z * wc;
        r.w = a.w * wa + b2.w * wb + c2.w * wc;
        *(float4*)&Xs[j * XSTR + c4 * 4] = r;
    }
    for (int e = t; e < TR * CU; e += 256) {
        int j = e / CU, c = e % CU;
        Xs[j * XSTR + CK + c] = ufeat[(size_t)(r0 + j) * CU + c];
    }
    if constexpr (CI16A > CH) {
        constexpr int PADN = CI16A - CH;
        for (int e = t; e < TR * PADN; e += 256) {
            int j = e / PADN, c = e % PADN;
            Xs[j * XSTR + CH + c] = 0.f;
        }
    }
    // MLP phases (each phase begins with __syncthreads inside its k-loop)
    gemm_phase<TR, XSTR, CH, C1, false>(Xs, Ws, w0, g0, b0,
                                        nullptr, nullptr, nullptr, nullptr, 0, t);
    gemm_phase<TR, XSTR, C1, C2, false>(Xs, Ws, w1, g1, b1,
                                        nullptr, nullptr, nullptr, nullptr, 0, t);
    if constexpr (FINAL) {
        gemm_phase<TR, XSTR, C2, 512, true>(Xs, Ws, fw, nullptr, nullptr,
                                            fb, fg, fbe, out, r0, t);
    } else {
        for (int e = t; e < TR * C2; e += 256) {
            int j = e / C2, c = e % C2;
            out[(size_t)(r0 + j) * C2 + c] = Xs[j * XSTR + c];
        }
    }
}

extern "C" void kernel_launch(void* const* d_in, const int* in_sizes, int n_in,
                              void* d_out, int out_size, void* d_ws, size_t ws_size,
                              hipStream_t stream) {
    (void)in_sizes; (void)n_in; (void)out_size; (void)ws_size;
    const float* xyz   = (const float*)d_in[0];
    const float* feats = (const float*)d_in[1];  // [B,N,3] — already point-major
    const float* sa1_w0 = (const float*)d_in[2];
    const float* sa1_g0 = (const float*)d_in[3];
    const float* sa1_b0 = (const float*)d_in[4];
    const float* sa1_w1 = (const float*)d_in[5];
    const float* sa1_g1 = (const float*)d_in[6];
    const float* sa1_b1 = (const float*)d_in[7];
    const float* sa2_w0 = (const float*)d_in[8];
    const float* sa2_g0 = (const float*)d_in[9];
    const float* sa2_b0 = (const float*)d_in[10];
    const float* sa2_w1 = (const float*)d_in[11];
    const float* sa2_g1 = (const float*)d_in[12];
    const float* sa2_b1 = (const float*)d_in[13];
    const float* sa3_w0 = (const float*)d_in[14];
    const float* sa3_g0 = (const float*)d_in[15];
    const float* sa3_b0 = (const float*)d_in[16];
    const float* sa3_w1 = (const float*)d_in[17];
    const float* sa3_g1 = (const float*)d_in[18];
    const float* sa3_b1 = (const float*)d_in[19];
    const float* fp3_w0 = (const float*)d_in[20];
    const float* fp3_g0 = (const float*)d_in[21];
    const float* fp3_b0 = (const float*)d_in[22];
    const float* fp3_w1 = (const float*)d_in[23];
    const float* fp3_g1 = (const float*)d_in[24];
    const float* fp3_b1 = (const float*)d_in[25];
    const float* fp2_w0 = (const float*)d_in[26];
    const float* fp2_g0 = (const float*)d_in[27];
    const float* fp2_b0 = (const float*)d_in[28];
    const float* fp2_w1 = (const float*)d_in[29];
    const float* fp2_g1 = (const float*)d_in[30];
    const float* fp2_b1 = (const float*)d_in[31];
    const float* fp1_w0 = (const float*)d_in[32];
    const float* fp1_g0 = (const float*)d_in[33];
    const float* fp1_b0 = (const float*)d_in[34];
    const float* fp1_w1 = (const float*)d_in[35];
    const float* fp1_g1 = (const float*)d_in[36];
    const float* fp1_b1 = (const float*)d_in[37];
    const float* fin_w  = (const float*)d_in[38];
    const float* fin_b  = (const float*)d_in[39];
    const float* fin_g  = (const float*)d_in[40];
    const float* fin_be = (const float*)d_in[41];

    // workspace layout (all point-major)
    float* ws = (float*)d_ws;
    float* l1x  = ws;                 // 16*256*3    = 12288
    float* l1f  = l1x + 12288;        // 16*256*128  = 524288
    float* l2x  = l1f + 524288;       // 16*64*3     = 3072
    float* l2f  = l2x + 3072;         // 16*64*256   = 262144
    float* l3x  = l2f + 262144;       // 16*16*3     = 768
    float* l3f  = l3x + 768;          // 16*16*512   = 131072
    float* l2fb = l3f + 131072;       // 16*64*256   = 262144
    float* l1fb = l2fb + 262144;      // 16*256*128  = 524288
    int* fidx1 = (int*)(l1fb + 524288);  // 16*256
    int* fidx2 = fidx1 + 4096;           // 16*64
    int* fidx3 = fidx2 + 1024;           // 16*16

    const float R2_1 = (float)(0.04 * 0.04);
    const float R2_2 = (float)(0.08 * 0.08);
    const float R2_3 = (float)(0.16 * 0.16);

    fps_kernel<4096, 256><<<16, 256, 0, stream>>>(xyz, fidx1);
    sa_kernel<3, 64, 128><<<16 * 256, 256, 0, stream>>>(
        xyz, feats, fidx1, sa1_w0, sa1_g0, sa1_b0, sa1_w1, sa1_g1, sa1_b1,
        l1x, l1f, 4096, 256, R2_1);

    fps_kernel<256, 64><<<16, 256, 0, stream>>>(l1x, fidx2);
    sa_kernel<128, 128, 256><<<16 * 64, 256, 0, stream>>>(
        l1x, l1f, fidx2, sa2_w0, sa2_g0, sa2_b0, sa2_w1, sa2_g1, sa2_b1,
        l2x, l2f, 256, 64, R2_2);

    fps_kernel<64, 16><<<16, 256, 0, stream>>>(l2x, fidx3);
    sa_kernel<256, 256, 512><<<16 * 16, 256, 0, stream>>>(
        l2x, l2f, fidx3, sa3_w0, sa3_g0, sa3_b0, sa3_w1, sa3_g1, sa3_b1,
        l3x, l3f, 64, 16, R2_3);

    // FP3: unk=l2 (NU=64, 1024 rows), kn=l3 (M=16), CK=512, CU=256 -> 256
    fp_kernel<16, 512, 256, 256, 256, 16, false><<<1024 / 16, 256, 0, stream>>>(
        l2x, l3x, l2f, l3f, fp3_w0, fp3_g0, fp3_b0, fp3_w1, fp3_g1, fp3_b1,
        nullptr, nullptr, nullptr, nullptr, l2fb, 64);

    // FP2: unk=l1 (NU=256, 4096 rows), kn=l2 (M=64), CK=256, CU=128 -> 128
    fp_kernel<64, 256, 128, 128, 128, 32, false><<<4096 / 32, 256, 0, stream>>>(
        l1x, l2x, l1f, l2fb, fp2_w0, fp2_g0, fp2_b0, fp2_w1, fp2_g1, fp2_b1,
        nullptr, nullptr, nullptr, nullptr, l1fb, 256);

    // FP1: unk=xyz (NU=4096, 65536 rows), kn=l1 (M=256), CK=128, CU=3 -> 128,
    // fused final 128->512 straight to d_out
    fp_kernel<256, 128, 3, 128, 128, 64, true><<<65536 / 64, 256, 0, stream>>>(
        xyz, l1x, feats, l1fb, fp1_w0, fp1_g0, fp1_b0, fp1_w1, fp1_g1, fp1_b1,
        fin_w, fin_b, fin_g, fin_be, (float*)d_out, 4096);
}

// Round 3
// 1162.770 us; speedup vs baseline: 2.6199x; 1.1441x over previous
//
#include <hip/hip_runtime.h>

#define DEVI __device__ __forceinline__
typedef unsigned long long u64;

static constexpr float BN_INV_F = 0.9999950000374997f; // 1/sqrt(1+1e-5), f32-rounded

// exact (non-contracted) squared distance, matching ((dx^2+dy^2)+dz^2) in f32
DEVI float d2rn(float ax, float ay, float az, float bx, float by, float bz) {
    float dx = __fsub_rn(ax, bx), dy = __fsub_rn(ay, by), dz = __fsub_rn(az, bz);
    return __fadd_rn(__fadd_rn(__fmul_rn(dx, dx), __fmul_rn(dy, dy)), __fmul_rn(dz, dz));
}

DEVI u64 shfl_xor_u64(u64 x, int m) {
    unsigned lo = (unsigned)x, hi = (unsigned)(x >> 32);
    lo = (unsigned)__shfl_xor((int)lo, m, 64);
    hi = (unsigned)__shfl_xor((int)hi, m, 64);
    return ((u64)hi << 32) | lo;
}
DEVI u64 umin64(u64 a, u64 b) { return a < b ? a : b; }
DEVI u64 umax64(u64 a, u64 b) { return a > b ? a : b; }

// ---------------- furthest point sampling ----------------
template <int N, int NPOINT, int BS>
__global__ __launch_bounds__(BS) void fps_kernel(const float* __restrict__ xyz,
                                                 int* __restrict__ fidx) {
    constexpr int PPT = N / BS;
    constexpr int NW = BS / 64;
    __shared__ float xsx[N], xsy[N], xsz[N];
    __shared__ u64 wmax[NW];
    __shared__ float q[3];
    const int t = threadIdx.x, b = blockIdx.x, lane = t & 63, wv = t >> 6;
    const float* xb = xyz + (size_t)b * N * 3;
    for (int p = t; p < N; p += BS) {
        xsx[p] = xb[p * 3]; xsy[p] = xb[p * 3 + 1]; xsz[p] = xb[p * 3 + 2];
    }
    float dist[PPT];
#pragma unroll
    for (int i = 0; i < PPT; ++i) dist[i] = 1e10f;
    if (t == 0) fidx[b * NPOINT] = 0;
    __syncthreads();
    if (t == 0) { q[0] = xsx[0]; q[1] = xsy[0]; q[2] = xsz[0]; }
    __syncthreads();
    for (int it = 1; it < NPOINT; ++it) {
        float qx = q[0], qy = q[1], qz = q[2];
        u64 best = 0ull;
#pragma unroll
        for (int i = 0; i < PPT; ++i) {
            int p = i * BS + t;
            float d = d2rn(xsx[p], xsy[p], xsz[p], qx, qy, qz);
            float nd = fminf(dist[i], d);
            dist[i] = nd;
            u64 pk = ((u64)__float_as_uint(nd) << 32) | (unsigned)(0xFFFFFFFFu - (unsigned)p);
            if (pk > best) best = pk;
        }
#pragma unroll
        for (int m = 1; m < 64; m <<= 1) best = umax64(best, shfl_xor_u64(best, m));
        if constexpr (NW > 1) {
            if (lane == 0) wmax[wv] = best;
            __syncthreads();
            if (wv == 0) {
                u64 m2 = wmax[lane < NW ? lane : 0];
#pragma unroll
                for (int m = 1; m < NW; m <<= 1) m2 = umax64(m2, shfl_xor_u64(m2, m));
                if (lane == 0) {
                    int p = (int)(0xFFFFFFFFu - (unsigned)m2);
                    q[0] = xsx[p]; q[1] = xsy[p]; q[2] = xsz[p];
                    fidx[b * NPOINT + it] = p;
                }
            }
        } else {
            if (lane == 0) {
                int p = (int)(0xFFFFFFFFu - (unsigned)best);
                q[0] = xsx[p]; q[1] = xsy[p]; q[2] = xsz[p];
                fidx[b * NPOINT + it] = p;
            }
        }
        __syncthreads();
    }
}

// ---------------- SA module: ball query + group + MLP(2) + maxpool ----------------
template <int CIN, int C1, int C2>
__global__ __launch_bounds__(256) void sa_kernel(
    const float* __restrict__ xyz, const float* __restrict__ feats,
    const int* __restrict__ fidx,
    const float* __restrict__ w0, const float* __restrict__ g0, const float* __restrict__ b0,
    const float* __restrict__ w1, const float* __restrict__ g1, const float* __restrict__ b1,
    float* __restrict__ oxyz, float* __restrict__ ofeat,
    int N, int S, float r2) {
    constexpr int NS = 16, C = 3 + CIN;
    __shared__ float h0[NS][C];
    __shared__ float h1[NS][C1];
    __shared__ int ids[NS];
    __shared__ int wsum[4];
    __shared__ float q[3];
    const int t = threadIdx.x;
    const int s = blockIdx.x % S, b = blockIdx.x / S;
    const float* xb = xyz + (size_t)b * N * 3;
    if (t == 0) {
        int qi = fidx[b * S + s];
        float qx = xb[qi * 3], qy = xb[qi * 3 + 1], qz = xb[qi * 3 + 2];
        q[0] = qx; q[1] = qy; q[2] = qz;
        float* op = oxyz + ((size_t)b * S + s) * 3;
        op[0] = qx; op[1] = qy; op[2] = qz;
    }
    __syncthreads();
    const float qx = q[0], qy = q[1], qz = q[2];
    const int chunk = (N + 255) / 256;
    const int lo = t * chunk, hi = min(N, lo + chunk);
    int c0 = 0;
    for (int p = lo; p < hi; ++p)
        if (d2rn(xb[p * 3], xb[p * 3 + 1], xb[p * 3 + 2], qx, qy, qz) < r2) c0++;
    const int lane = t & 63, wv = t >> 6;
    int v = c0;
    for (int off = 1; off < 64; off <<= 1) {
        int n = __shfl_up(v, off, 64);
        if (lane >= off) v += n;
    }
    if (lane == 63) wsum[wv] = v;
    __syncthreads();
    int pre = 0;
    for (int i = 0; i < wv; ++i) pre += wsum[i];
    const int total = wsum[0] + wsum[1] + wsum[2] + wsum[3];
    int rank = pre + v - c0;
    if (rank < NS && c0 > 0) {
        for (int p = lo; p < hi && rank < NS; ++p) {
            if (d2rn(xb[p * 3], xb[p * 3 + 1], xb[p * 3 + 2], qx, qy, qz) < r2) {
                ids[rank] = p;
                rank++;
            }
        }
    }
    __syncthreads();
    if (t == 0) {
        int cnt = min(total, NS);
        for (int r = cnt; r < NS; ++r) ids[r] = ids[0];
    }
    __syncthreads();
    for (int e = t; e < NS * C; e += 256) {
        int k = e / C, c = e % C;
        int p = ids[k];
        float val = (c < 3) ? __fsub_rn(xb[p * 3 + c], q[c])
                            : feats[((size_t)b * N + p) * CIN + (c - 3)];
        h0[k][c] = val;
    }
    __syncthreads();
    for (int e = t; e < NS * C1; e += 256) {
        int k = e / C1, o = e % C1;
        const float* wr = w0 + (size_t)o * C;
        float acc = 0.f;
        for (int c = 0; c < C; ++c) acc = fmaf(h0[k][c], wr[c], acc);
        h1[k][o] = fmaxf(fmaf(acc, g0[o] * BN_INV_F, b0[o]), 0.f);
    }
    __syncthreads();
    for (int o = t; o < C2; o += 256) {
        const float* wr = w1 + (size_t)o * C1;
        float accs[NS];
#pragma unroll
        for (int k = 0; k < NS; ++k) accs[k] = 0.f;
        for (int c = 0; c < C1; ++c) {
            float wvv = wr[c];
#pragma unroll
            for (int k = 0; k < NS; ++k) accs[k] = fmaf(h1[k][c], wvv, accs[k]);
        }
        float scale = g1[o] * BN_INV_F, bb = b1[o];
        float m = -1e30f;
#pragma unroll
        for (int k = 0; k < NS; ++k) m = fmaxf(m, fmaxf(fmaf(accs[k], scale, bb), 0.f));
        ofeat[((size_t)b * S + s) * C2 + o] = m;
    }
}

// ---------------- register-tiled GEMM phase with reg-prefetch W staging ----------------
// 256 threads = 16(ty) x 16(tx); thread tile RT rows x 8 cols. Xs swizzled:
// float4 index c4 -> c4 ^ ((row/RT)&3)  => a wave's 4 ty-rows hit 4 distinct bank groups.
template <int TR, int XSTR, int CI, int CO, bool EPI>
DEVI void gemm_phase(float* Xs, float* Ws,
                     const float* __restrict__ W, const float* __restrict__ g,
                     const float* __restrict__ bt,
                     const float* __restrict__ fb, const float* __restrict__ fg,
                     const float* __restrict__ fbe,
                     float* __restrict__ gout, int r0, int t) {
    constexpr int RT = TR / 16;
    constexpr int CC = CO / 128;
    constexpr int CI16 = ((CI + 15) / 16) * 16;
    constexpr int NCH = CI16 / 16;
    constexpr int NQ = CC * NCH;
    constexpr int XSTR4 = XSTR / 4;
    const int tx = t & 15, ty = t >> 4;
    constexpr int AC = EPI ? 1 : CC;
    float acc[AC][RT][8];
    if constexpr (!EPI) {
#pragma unroll
        for (int a = 0; a < AC; ++a)
#pragma unroll
            for (int r = 0; r < RT; ++r)
#pragma unroll
                for (int i = 0; i < 8; ++i) acc[a][r][i] = 0.f;
    }
    float pre[8];
    {   // prologue prefetch chunk 0
#pragma unroll
        for (int i = 0; i < 8; ++i) {
            int e = t + 256 * i, row = e >> 4, k = e & 15;
            pre[i] = (k < CI) ? W[(size_t)row * CI + k] : 0.f;
        }
    }
    for (int qq = 0; qq < NQ; ++qq) {
        int cc = qq / NCH, k0 = (qq % NCH) * 16;
        if (EPI && (qq % NCH) == 0) {
#pragma unroll
            for (int r = 0; r < RT; ++r)
#pragma unroll
                for (int i = 0; i < 8; ++i) acc[0][r][i] = 0.f;
        }
        __syncthreads();   // waves done reading previous Ws chunk
#pragma unroll
        for (int i = 0; i < 8; ++i) {
            int e = t + 256 * i;
            Ws[(e >> 4) * 20 + (e & 15)] = pre[i];
        }
        __syncthreads();
        if (qq + 1 < NQ) {   // prefetch next chunk while computing
            int cn = (qq + 1) / NCH, kn = ((qq + 1) % NCH) * 16;
#pragma unroll
            for (int i = 0; i < 8; ++i) {
                int e = t + 256 * i, row = e >> 4, kk = e & 15, k = kn + kk;
                pre[i] = (k < CI) ? W[(size_t)(cn * 128 + row) * CI + k] : 0.f;
            }
        }
        const int a = EPI ? 0 : cc;
#pragma unroll
        for (int k4 = 0; k4 < 4; ++k4) {
            float4 wv[8];
#pragma unroll
            for (int i = 0; i < 8; ++i)
                wv[i] = *(const float4*)&Ws[(tx + 16 * i) * 20 + k4 * 4];
#pragma unroll
            for (int r = 0; r < RT; ++r) {
                int c4 = (k0 >> 2) + k4;
                float4 xv = *(const float4*)&Xs[((ty * RT + r) * XSTR4 + (c4 ^ (ty & 3))) * 4];
#pragma unroll
                for (int i = 0; i < 8; ++i) {
                    acc[a][r][i] = fmaf(xv.x, wv[i].x, acc[a][r][i]);
                    acc[a][r][i] = fmaf(xv.y, wv[i].y, acc[a][r][i]);
                    acc[a][r][i] = fmaf(xv.z, wv[i].z, acc[a][r][i]);
                    acc[a][r][i] = fmaf(xv.w, wv[i].w, acc[a][r][i]);
                }
            }
        }
        if (EPI && ((qq + 1) % NCH) == 0) {   // flush this cc's columns to global
#pragma unroll
            for (int i = 0; i < 8; ++i) {
                int c = cc * 128 + tx + 16 * i;
                float bia = fb[c], sc = fg[c] * BN_INV_F, be = fbe[c];
#pragma unroll
                for (int r = 0; r < RT; ++r) {
                    float val = fmaxf(fmaf(acc[0][r][i] + bia, sc, be), 0.f);
                    gout[(size_t)(r0 + ty * RT + r) * 512 + c] = val;
                }
            }
        }
    }
    if constexpr (!EPI) {
        __syncthreads();
#pragma unroll
        for (int cc = 0; cc < CC; ++cc)
#pragma unroll
            for (int i = 0; i < 8; ++i) {
                int c = cc * 128 + tx + 16 * i;
                float sc = g[c] * BN_INV_F, bb = bt[c];
#pragma unroll
                for (int r = 0; r < RT; ++r) {
                    int row = ty * RT + r;
                    int addr = (row * XSTR4 + ((c >> 2) ^ (ty & 3))) * 4 + (c & 3);
                    Xs[addr] = fmaxf(fmaf(acc[cc][r][i], sc, bb), 0.f);
                }
            }
        __syncthreads();
    }
}

// ---------------- FP module: wave-parallel 3-NN + interp + tiled MLP [+ fused final] ----------------
template <int M, int CK, int CU, int C1, int C2, int TR, bool FINAL>
__global__ __launch_bounds__(256) void fp_kernel(
    const float* __restrict__ uxyz, const float* __restrict__ kxyz,
    const float* __restrict__ ufeat, const float* __restrict__ kfeat,
    const float* __restrict__ w0, const float* __restrict__ g0, const float* __restrict__ b0,
    const float* __restrict__ w1, const float* __restrict__ g1, const float* __restrict__ b1,
    const float* __restrict__ fw, const float* __restrict__ fb,
    const float* __restrict__ fg, const float* __restrict__ fbe,
    float* __restrict__ out, int NU) {
    constexpr int CH = CK + CU;
    constexpr int CI16A = ((CH + 15) / 16) * 16;
    constexpr int XSTR = CI16A;
    constexpr int XSTR4 = XSTR / 4;
    constexpr int RT = TR / 16;
    __shared__ __align__(16) float Xs[TR * XSTR];
    __shared__ __align__(16) float Ws[128 * 20];
    __shared__ float kxs[M * 3];
    const int t = threadIdx.x, lane = t & 63, wv = t >> 6;
    const int r0 = blockIdx.x * TR;
    const int b = r0 / NU;
    for (int e = t; e < M * 3; e += 256) kxs[e] = kxyz[(size_t)b * M * 3 + e];
    __syncthreads();
    // phase A: per wave, one row at a time: wave-parallel exact 3-NN + interp fill
    for (int j = wv; j < TR; j += 4) {
        const int r = r0 + j;
        const int sw = (j / RT) & 3;  // swizzle field for this row
        const float* up = uxyz + (size_t)r * 3;
        float ux = up[0], uy = up[1], uz = up[2];
        u64 a0 = ~0ull, a1 = ~0ull, a2 = ~0ull;
        for (int k = lane; k < M; k += 64) {
            float d = d2rn(kxs[k * 3], kxs[k * 3 + 1], kxs[k * 3 + 2], ux, uy, uz);
            u64 key = ((u64)__float_as_uint(d) << 32) | (unsigned)k;
            if (key < a0)      { a2 = a1; a1 = a0; a0 = key; }
            else if (key < a1) { a2 = a1; a1 = key; }
            else if (key < a2) { a2 = key; }
        }
#pragma unroll
        for (int m = 1; m < 64; m <<= 1) {   // merge sorted triples (exact order stats)
            u64 b0 = shfl_xor_u64(a0, m), b1 = shfl_xor_u64(a1, m), b2 = shfl_xor_u64(a2, m);
            u64 c0 = umin64(a0, b0);
            u64 c1 = umin64(umax64(a0, b0), umin64(a1, b1));
            u64 c2 = umin64(umin64(umax64(a1, b0), umax64(a0, b1)), umin64(a2, b2));
            a0 = c0; a1 = c1; a2 = c2;
        }
        int s0 = (int)(unsigned)a0, s1 = (int)(unsigned)a1, s2 = (int)(unsigned)a2;
        float d0 = __uint_as_float((unsigned)(a0 >> 32));
        float d1 = __uint_as_float((unsigned)(a1 >> 32));
        float dd2 = __uint_as_float((unsigned)(a2 >> 32));
        float wa = 1.0f / (d0 + 1e-8f), wb = 1.0f / (d1 + 1e-8f), wc = 1.0f / (dd2 + 1e-8f);
        float sum = (wa + wb) + wc;
        wa /= sum; wb /= sum; wc /= sum;
        const float* kb = kfeat + (size_t)b * M * CK;
        for (int c4 = lane; c4 < CK / 4; c4 += 64) {
            float4 va = *(const float4*)(kb + (size_t)s0 * CK + c4 * 4);
            float4 vb = *(const float4*)(kb + (size_t)s1 * CK + c4 * 4);
            float4 vc = *(const float4*)(kb + (size_t)s2 * CK + c4 * 4);
            float4 rr;
            rr.x = va.x * wa + vb.x * wb + vc.x * wc;
            rr.y = va.y * wa + vb.y * wb + vc.y * wc;
            rr.z = va.z * wa + vb.z * wb + vc.z * wc;
            rr.w = va.w * wa + vb.w * wb + vc.w * wc;
            *(float4*)&Xs[(j * XSTR4 + (c4 ^ sw)) * 4] = rr;
        }
        for (int c = CK + lane; c < CH; c += 64)
            Xs[(j * XSTR4 + ((c >> 2) ^ sw)) * 4 + (c & 3)] =
                ufeat[(size_t)r * CU + (c - CK)];
        for (int c = CH + lane; c < CI16A; c += 64)
            Xs[(j * XSTR4 + ((c >> 2) ^ sw)) * 4 + (c & 3)] = 0.f;
    }
    // MLP phases (first barrier inside gemm_phase orders fill vs reads)
    gemm_phase<TR, XSTR, CH, C1, false>(Xs, Ws, w0, g0, b0,
                                        nullptr, nullptr, nullptr, nullptr, 0, t);
    gemm_phase<TR, XSTR, C1, C2, false>(Xs, Ws, w1, g1, b1,
                                        nullptr, nullptr, nullptr, nullptr, 0, t);
    if constexpr (FINAL) {
        gemm_phase<TR, XSTR, C2, 512, true>(Xs, Ws, fw, nullptr, nullptr,
                                            fb, fg, fbe, out, r0, t);
    } else {
        for (int e = t; e < TR * C2; e += 256) {
            int j = e / C2, c = e % C2;
            int sw = (j / RT) & 3;
            out[(size_t)(r0 + j) * C2 + c] = Xs[(j * XSTR4 + ((c >> 2) ^ sw)) * 4 + (c & 3)];
        }
    }
}

extern "C" void kernel_launch(void* const* d_in, const int* in_sizes, int n_in,
                              void* d_out, int out_size, void* d_ws, size_t ws_size,
                              hipStream_t stream) {
    (void)in_sizes; (void)n_in; (void)out_size; (void)ws_size;
    const float* xyz   = (const float*)d_in[0];
    const float* feats = (const float*)d_in[1];  // [B,N,3] point-major
    const float* sa1_w0 = (const float*)d_in[2];
    const float* sa1_g0 = (const float*)d_in[3];
    const float* sa1_b0 = (const float*)d_in[4];
    const float* sa1_w1 = (const float*)d_in[5];
    const float* sa1_g1 = (const float*)d_in[6];
    const float* sa1_b1 = (const float*)d_in[7];
    const float* sa2_w0 = (const float*)d_in[8];
    const float* sa2_g0 = (const float*)d_in[9];
    const float* sa2_b0 = (const float*)d_in[10];
    const float* sa2_w1 = (const float*)d_in[11];
    const float* sa2_g1 = (const float*)d_in[12];
    const float* sa2_b1 = (const float*)d_in[13];
    const float* sa3_w0 = (const float*)d_in[14];
    const float* sa3_g0 = (const float*)d_in[15];
    const float* sa3_b0 = (const float*)d_in[16];
    const float* sa3_w1 = (const float*)d_in[17];
    const float* sa3_g1 = (const float*)d_in[18];
    const float* sa3_b1 = (const float*)d_in[19];
    const float* fp3_w0 = (const float*)d_in[20];
    const float* fp3_g0 = (const float*)d_in[21];
    const float* fp3_b0 = (const float*)d_in[22];
    const float* fp3_w1 = (const float*)d_in[23];
    const float* fp3_g1 = (const float*)d_in[24];
    const float* fp3_b1 = (const float*)d_in[25];
    const float* fp2_w0 = (const float*)d_in[26];
    const float* fp2_g0 = (const float*)d_in[27];
    const float* fp2_b0 = (const float*)d_in[28];
    const float* fp2_w1 = (const float*)d_in[29];
    const float* fp2_g1 = (const float*)d_in[30];
    const float* fp2_b1 = (const float*)d_in[31];
    const float* fp1_w0 = (const float*)d_in[32];
    const float* fp1_g0 = (const float*)d_in[33];
    const float* fp1_b0 = (const float*)d_in[34];
    const float* fp1_w1 = (const float*)d_in[35];
    const float* fp1_g1 = (const float*)d_in[36];
    const float* fp1_b1 = (const float*)d_in[37];
    const float* fin_w  = (const float*)d_in[38];
    const float* fin_b  = (const float*)d_in[39];
    const float* fin_g  = (const float*)d_in[40];
    const float* fin_be = (const float*)d_in[41];

    float* ws = (float*)d_ws;
    float* l1x  = ws;                 // 16*256*3    = 12288
    float* l1f  = l1x + 12288;        // 16*256*128  = 524288
    float* l2x  = l1f + 524288;       // 16*64*3     = 3072
    float* l2f  = l2x + 3072;         // 16*64*256   = 262144
    float* l3x  = l2f + 262144;       // 16*16*3     = 768
    float* l3f  = l3x + 768;          // 16*16*512   = 131072
    float* l2fb = l3f + 131072;       // 16*64*256   = 262144
    float* l1fb = l2fb + 262144;      // 16*256*128  = 524288
    int* fidx1 = (int*)(l1fb + 524288);  // 16*256
    int* fidx2 = fidx1 + 4096;           // 16*64
    int* fidx3 = fidx2 + 1024;           // 16*16

    const float R2_1 = (float)(0.04 * 0.04);
    const float R2_2 = (float)(0.08 * 0.08);
    const float R2_3 = (float)(0.16 * 0.16);

    fps_kernel<4096, 256, 1024><<<16, 1024, 0, stream>>>(xyz, fidx1);
    sa_kernel<3, 64, 128><<<16 * 256, 256, 0, stream>>>(
        xyz, feats, fidx1, sa1_w0, sa1_g0, sa1_b0, sa1_w1, sa1_g1, sa1_b1,
        l1x, l1f, 4096, 256, R2_1);

    fps_kernel<256, 64, 256><<<16, 256, 0, stream>>>(l1x, fidx2);
    sa_kernel<128, 128, 256><<<16 * 64, 256, 0, stream>>>(
        l1x, l1f, fidx2, sa2_w0, sa2_g0, sa2_b0, sa2_w1, sa2_g1, sa2_b1,
        l2x, l2f, 256, 64, R2_2);

    fps_kernel<64, 16, 64><<<16, 64, 0, stream>>>(l2x, fidx3);
    sa_kernel<256, 256, 512><<<16 * 16, 256, 0, stream>>>(
        l2x, l2f, fidx3, sa3_w0, sa3_g0, sa3_b0, sa3_w1, sa3_g1, sa3_b1,
        l3x, l3f, 64, 16, R2_3);

    // FP3: unk=l2 (1024 rows), kn=l3 (M=16), 768 -> 256 -> 256
    fp_kernel<16, 512, 256, 256, 256, 16, false><<<1024 / 16, 256, 0, stream>>>(
        l2x, l3x, l2f, l3f, fp3_w0, fp3_g0, fp3_b0, fp3_w1, fp3_g1, fp3_b1,
        nullptr, nullptr, nullptr, nullptr, l2fb, 64);

    // FP2: unk=l1 (4096 rows), kn=l2 (M=64), 384 -> 128 -> 128
    fp_kernel<64, 256, 128, 128, 128, 32, false><<<4096 / 32, 256, 0, stream>>>(
        l1x, l2x, l1f, l2fb, fp2_w0, fp2_g0, fp2_b0, fp2_w1, fp2_g1, fp2_b1,
        nullptr, nullptr, nullptr, nullptr, l1fb, 256);

    // FP1: unk=xyz (65536 rows), kn=l1 (M=256), 131 -> 128 -> 128, fused 128->512
    fp_kernel<256, 128, 3, 128, 128, 64, true><<<65536 / 64, 256, 0, stream>>>(
        xyz, l1x, feats, l1fb, fp1_w0, fp1_g0, fp1_b0, fp1_w1, fp1_g1, fp1_b1,
        fin_w, fin_b, fin_g, fin_be, (float*)d_out, 4096);
}

// Round 4
// 903.211 us; speedup vs baseline: 3.3727x; 1.2874x over previous
//
#include <hip/hip_runtime.h>

#define DEVI __device__ __forceinline__
typedef unsigned long long u64;

static constexpr float BN_INV_F = 0.9999950000374997f; // 1/sqrt(1+1e-5), f32-rounded

// exact (non-contracted) squared distance, matching ((dx^2+dy^2)+dz^2) in f32
DEVI float d2rn(float ax, float ay, float az, float bx, float by, float bz) {
    float dx = __fsub_rn(ax, bx), dy = __fsub_rn(ay, by), dz = __fsub_rn(az, bz);
    return __fadd_rn(__fadd_rn(__fmul_rn(dx, dx), __fmul_rn(dy, dy)), __fmul_rn(dz, dz));
}

DEVI u64 shfl_xor_u64(u64 x, int m) {
    unsigned lo = (unsigned)x, hi = (unsigned)(x >> 32);
    lo = (unsigned)__shfl_xor((int)lo, m, 64);
    hi = (unsigned)__shfl_xor((int)hi, m, 64);
    return ((u64)hi << 32) | lo;
}
DEVI u64 umin64(u64 a, u64 b) { return a < b ? a : b; }
DEVI u64 umax64(u64 a, u64 b) { return a > b ? a : b; }

// ---------------- furthest point sampling (1 barrier/iter, dbuf wmax) ----------------
template <int N, int NPOINT, int BS>
__global__ __launch_bounds__(BS) void fps_kernel(const float* __restrict__ xyz,
                                                 int* __restrict__ fidx) {
    constexpr int PPT = N / BS;
    constexpr int NW = BS / 64;
    __shared__ float xsx[N], xsy[N], xsz[N];
    __shared__ u64 wmax[2][NW > 0 ? NW : 1];
    const int t = threadIdx.x, b = blockIdx.x, lane = t & 63, wv = t >> 6;
    const float* xb = xyz + (size_t)b * N * 3;
    for (int p = t; p < N; p += BS) {
        xsx[p] = xb[p * 3]; xsy[p] = xb[p * 3 + 1]; xsz[p] = xb[p * 3 + 2];
    }
    float dist[PPT];
#pragma unroll
    for (int i = 0; i < PPT; ++i) dist[i] = 1e10f;
    if (t == 0) fidx[b * NPOINT] = 0;
    __syncthreads();
    float qx = xsx[0], qy = xsy[0], qz = xsz[0];
    for (int it = 1; it < NPOINT; ++it) {
        u64 best = 0ull;
#pragma unroll
        for (int i = 0; i < PPT; ++i) {
            int p = i * BS + t;
            float d = d2rn(xsx[p], xsy[p], xsz[p], qx, qy, qz);
            float nd = fminf(dist[i], d);
            dist[i] = nd;
            u64 pk = ((u64)__float_as_uint(nd) << 32) | (unsigned)(0xFFFFFFFFu - (unsigned)p);
            if (pk > best) best = pk;
        }
#pragma unroll
        for (int m = 1; m < 64; m <<= 1) best = umax64(best, shfl_xor_u64(best, m));
        if constexpr (NW > 1) {
            if (lane == 0) wmax[it & 1][wv] = best;
            __syncthreads();
            u64 m2 = wmax[it & 1][lane & (NW - 1)];
#pragma unroll
            for (int m = 1; m < NW; m <<= 1) m2 = umax64(m2, shfl_xor_u64(m2, m));
            best = m2;
        }
        int p = (int)(0xFFFFFFFFu - (unsigned)best);
        qx = xsx[p]; qy = xsy[p]; qz = xsz[p];
        if (t == 0) fidx[b * NPOINT + it] = p;
    }
}

// ---------------- shared GEMM phase: 8-k chunks, Ws double-buffer, 1 barrier/chunk --
// 256 threads = 16(ty) x 16(tx); thread tile RT rows x NCOL cols.
// Xs float4-swizzled by (row/RT)&3. MODE: 0 = BN+ReLU -> Xs; 1 = +bias,BN,ReLU -> gout;
// 2 = BN+ReLU + maxpool over 16-row groups via LDS atomicMax (values >= 0).
template <int TR, int XSTR, int CI, int CO, int MODE>
DEVI void gemm_phase(float* __restrict__ Xs, float* __restrict__ Ws,
                     const float* __restrict__ W,
                     const float* __restrict__ sA, const float* __restrict__ sB,
                     const float* __restrict__ fbias,
                     float* __restrict__ gout, int r0,
                     unsigned* __restrict__ mp, int t) {
    constexpr int RT = TR / 16;
    constexpr int NCOL = (CO / 16 < 8) ? (CO / 16) : 8;
    constexpr int ROWS = 16 * NCOL;
    constexpr int CC = CO / ROWS;
    constexpr int CI16 = ((CI + 15) / 16) * 16;
    constexpr int NCH = CI16 / 8;      // 8-k chunks (even, since CI16 % 16 == 0)
    constexpr int NQ = CC * NCH;
    constexpr int PRE = ROWS * 8 / 256;  // 2 or 4
    constexpr int XSTR4 = XSTR / 4;
    constexpr int AC = (MODE == 0) ? CC : 1;
    const int tx = t & 15, ty = t >> 4;
    float acc[AC][RT][NCOL];
    if constexpr (MODE == 0) {
#pragma unroll
        for (int a = 0; a < AC; ++a)
#pragma unroll
            for (int r = 0; r < RT; ++r)
#pragma unroll
                for (int i = 0; i < NCOL; ++i) acc[a][r][i] = 0.f;
    }
    float pre[PRE];
#pragma unroll
    for (int i = 0; i < PRE; ++i) {   // prefetch chunk 0
        int e = t + 256 * i, row = e >> 3, kk = e & 7;
        pre[i] = (kk < CI) ? W[(size_t)row * CI + kk] : 0.f;
    }
#pragma unroll
    for (int i = 0; i < PRE; ++i) {   // prologue stage -> Ws[0]
        int e = t + 256 * i;
        Ws[(e >> 3) * 12 + (e & 7)] = pre[i];
    }
#pragma unroll
    for (int cc = 0; cc < CC; ++cc) {
        if constexpr (MODE != 0) {
#pragma unroll
            for (int r = 0; r < RT; ++r)
#pragma unroll
                for (int i = 0; i < NCOL; ++i) acc[0][r][i] = 0.f;
        }
        for (int kc = 0; kc < NCH; ++kc) {
            const int qq = cc * NCH + kc, buf = kc & 1;
            __syncthreads();   // Ws[buf] staged & previous readers done
            if (qq + 1 < NQ) { // issue next chunk's global loads early (T14)
                const int cn = (qq + 1) / NCH, kn = ((qq + 1) % NCH) * 8;
#pragma unroll
                for (int i = 0; i < PRE; ++i) {
                    int e = t + 256 * i, row = e >> 3, k = kn + (e & 7);
                    pre[i] = (k < CI) ? W[(size_t)(cn * ROWS + row) * CI + k] : 0.f;
                }
            }
            const float* wsb = Ws + buf * 1536;
#pragma unroll
            for (int k4i = 0; k4i < 2; ++k4i) {
                const int c4 = kc * 2 + k4i;
                float4 wv[NCOL];
#pragma unroll
                for (int i = 0; i < NCOL; ++i)
                    wv[i] = *(const float4*)&wsb[(tx + 16 * i) * 12 + k4i * 4];
#pragma unroll
                for (int r = 0; r < RT; ++r) {
                    float4 xv = *(const float4*)
                        &Xs[(((ty * RT + r) * XSTR4) + (c4 ^ (ty & 3))) * 4];
                    float* A;
                    if constexpr (MODE == 0) A = acc[cc][r]; else A = acc[0][r];
#pragma unroll
                    for (int i = 0; i < NCOL; ++i) {
                        A[i] = fmaf(xv.x, wv[i].x, A[i]);
                        A[i] = fmaf(xv.y, wv[i].y, A[i]);
                        A[i] = fmaf(xv.z, wv[i].z, A[i]);
                        A[i] = fmaf(xv.w, wv[i].w, A[i]);
                    }
                }
            }
            if (qq + 1 < NQ) {   // write-late: stage next chunk into the other buffer
                float* wsn = Ws + (buf ^ 1) * 1536;
#pragma unroll
                for (int i = 0; i < PRE; ++i) {
                    int e = t + 256 * i;
                    wsn[(e >> 3) * 12 + (e & 7)] = pre[i];
                }
            }
        }
        if constexpr (MODE == 1) {
#pragma unroll
            for (int i = 0; i < NCOL; ++i) {
                int c = cc * ROWS + tx + 16 * i;
                float bia = fbias[c], sc = sA[c] * BN_INV_F, be = sB[c];
#pragma unroll
                for (int r = 0; r < RT; ++r) {
                    float val = fmaxf(fmaf(acc[0][r][i] + bia, sc, be), 0.f);
                    gout[(size_t)(r0 + ty * RT + r) * CO + c] = val;
                }
            }
        } else if constexpr (MODE == 2) {
#pragma unroll
            for (int i = 0; i < NCOL; ++i) {
                int c = cc * ROWS + tx + 16 * i;
                float sc = sA[c] * BN_INV_F, bb = sB[c];
#pragma unroll
                for (int r = 0; r < RT; ++r) {
                    float val = fmaxf(fmaf(acc[0][r][i], sc, bb), 0.f);
                    atomicMax(&mp[((ty * RT + r) >> 4) * CO + c], __float_as_uint(val));
                }
            }
        }
    }
    if constexpr (MODE == 0) {
        __syncthreads();
#pragma unroll
        for (int cc = 0; cc < CC; ++cc)
#pragma unroll
            for (int i = 0; i < NCOL; ++i) {
                int c = cc * ROWS + tx + 16 * i;
                float sc = sA[c] * BN_INV_F, bb = sB[c];
#pragma unroll
                for (int r = 0; r < RT; ++r) {
                    int row = ty * RT + r;
                    Xs[(row * XSTR4 + ((c >> 2) ^ (ty & 3))) * 4 + (c & 3)] =
                        fmaxf(fmaf(acc[cc][r][i], sc, bb), 0.f);
                }
            }
        __syncthreads();
    }
}

// ---------------- SA module: wave ball-query + grouped fill + GEMM MLP + maxpool ----
template <int N, int S, int CIN, int C1, int C2, int TR>
__global__ __launch_bounds__(256) void sa_kernel(
    const float* __restrict__ xyz, const float* __restrict__ feats,
    const int* __restrict__ fidx,
    const float* __restrict__ w0, const float* __restrict__ g0, const float* __restrict__ b0,
    const float* __restrict__ w1, const float* __restrict__ g1, const float* __restrict__ b1,
    float* __restrict__ oxyz, float* __restrict__ ofeat, float r2) {
    constexpr int QPB = TR / 16;
    constexpr int C = 3 + CIN;
    constexpr int CI16 = ((C + 15) / 16) * 16;
    constexpr int XSTR = (CI16 > C1) ? CI16 : C1;
    constexpr int XSTR4 = XSTR / 4;
    constexpr int RTl = TR / 16;
    __shared__ __align__(16) float Xs[TR * XSTR];
    __shared__ __align__(16) float Ws[2 * 128 * 12];
    __shared__ int ids[QPB][16];
    __shared__ float qp[QPB][3];
    __shared__ unsigned mp[(TR / 16) * C2];
    const int t = threadIdx.x, lane = t & 63, wv = t >> 6;
    const int q0 = blockIdx.x * QPB;
    // ball query: one wave per query, ordered ballot emission, early exit
    for (int q = wv; q < QPB; q += 4) {
        const int sq = q0 + q, bb = sq / S;
        const float* xb = xyz + (size_t)bb * N * 3;
        const int qi = fidx[sq];
        const float qx = xb[qi * 3], qy = xb[qi * 3 + 1], qz = xb[qi * 3 + 2];
        if (lane == 0) {
            qp[q][0] = qx; qp[q][1] = qy; qp[q][2] = qz;
            float* op = oxyz + (size_t)sq * 3;
            op[0] = qx; op[1] = qy; op[2] = qz;
        }
        int base = 0;
        for (int seg = 0; seg < N; seg += 64) {
            const int p = seg + lane;
            float d = d2rn(xb[p * 3], xb[p * 3 + 1], xb[p * 3 + 2], qx, qy, qz);
            bool hit = d < r2;
            u64 mask = __ballot(hit);
            int before = (int)__popcll(mask & ((1ull << lane) - 1ull));
            if (hit && base + before < 16) ids[q][base + before] = p;
            base += (int)__popcll(mask);
            if (base >= 16) break;
        }
        if (lane == 0) {
            int cnt = base < 16 ? base : 16;   // cnt >= 1 (query point hits itself)
            int first = ids[q][0];
            for (int r = cnt; r < 16; ++r) ids[q][r] = first;
        }
    }
    __syncthreads();
    // fill Xs rows (swizzled): [dxyz(3) | feats(CIN) | 0-pad]
    if constexpr (CIN == 3) {
        for (int e = t; e < TR * CI16; e += 256) {
            int j = e / CI16, c = e % CI16;
            int q = j >> 4, p = ids[q][j & 15];
            int bb = (q0 + q) / S;
            float v = 0.f;
            if (c < 3) v = __fsub_rn(xyz[((size_t)bb * N + p) * 3 + c], qp[q][c]);
            else if (c < C) v = feats[((size_t)bb * N + p) * CIN + (c - 3)];
            Xs[(j * XSTR4 + ((c >> 2) ^ ((j / RTl) & 3))) * 4 + (c & 3)] = v;
        }
    } else {
        for (int e = t; e < TR * 16; e += 256) {   // xyz cols + zero-pad cols
            int j = e / 16, ci = e % 16;
            int q = j >> 4, p = ids[q][j & 15];
            int bb = (q0 + q) / S;
            int c = (ci < 3) ? ci : (C + ci - 3);
            if (c >= CI16) continue;
            float v = (ci < 3) ? __fsub_rn(xyz[((size_t)bb * N + p) * 3 + ci], qp[q][ci]) : 0.f;
            Xs[(j * XSTR4 + ((c >> 2) ^ ((j / RTl) & 3))) * 4 + (c & 3)] = v;
        }
        for (int e = t; e < TR * (CIN / 4); e += 256) {
            int j = e / (CIN / 4), c4i = e % (CIN / 4);
            int q = j >> 4, p = ids[q][j & 15];
            int bb = (q0 + q) / S;
            float4 v = *(const float4*)&feats[((size_t)bb * N + p) * CIN + c4i * 4];
            int sw = (j / RTl) & 3;
            float vv[4] = {v.x, v.y, v.z, v.w};
#pragma unroll
            for (int u = 0; u < 4; ++u) {
                int c = 3 + c4i * 4 + u;
                Xs[(j * XSTR4 + ((c >> 2) ^ sw)) * 4 + (c & 3)] = vv[u];
            }
        }
    }
    gemm_phase<TR, XSTR, C, C1, 0>(Xs, Ws, w0, g0, b0, nullptr, nullptr, 0, nullptr, t);
    for (int e = t; e < (TR / 16) * C2; e += 256) mp[e] = 0u;
    gemm_phase<TR, XSTR, C1, C2, 2>(Xs, Ws, w1, g1, b1, nullptr, nullptr, 0, mp, t);
    __syncthreads();
    for (int e = t; e < QPB * C2; e += 256) {
        int q = e / C2, c = e % C2;
        ofeat[(size_t)(q0 + q) * C2 + c] = __uint_as_float(mp[e]);
    }
}

// ---------------- FP module: wave 3-NN + interp + GEMM MLP [+ fused final] ----------
template <int M, int CK, int CU, int C1, int C2, int TR, bool FINAL>
__global__ __launch_bounds__(256) void fp_kernel(
    const float* __restrict__ uxyz, const float* __restrict__ kxyz,
    const float* __restrict__ ufeat, const float* __restrict__ kfeat,
    const float* __restrict__ w0, const float* __restrict__ g0, const float* __restrict__ b0,
    const float* __restrict__ w1, const float* __restrict__ g1, const float* __restrict__ b1,
    const float* __restrict__ fw, const float* __restrict__ fb,
    const float* __restrict__ fg, const float* __restrict__ fbe,
    float* __restrict__ out, int NU) {
    constexpr int CH = CK + CU;
    constexpr int CI16A = ((CH + 15) / 16) * 16;
    constexpr int XSTR = CI16A;
    constexpr int XSTR4 = XSTR / 4;
    constexpr int RT = TR / 16;
    __shared__ __align__(16) float Xs[TR * XSTR];
    __shared__ __align__(16) float Ws[2 * 128 * 12];
    __shared__ float kxs[M * 3];
    const int t = threadIdx.x, lane = t & 63, wv = t >> 6;
    const int r0 = blockIdx.x * TR;
    const int b = r0 / NU;
    for (int e = t; e < M * 3; e += 256) kxs[e] = kxyz[(size_t)b * M * 3 + e];
    __syncthreads();
    // wave-parallel exact 3-NN + interp fill
    for (int j = wv; j < TR; j += 4) {
        const int r = r0 + j;
        const int sw = (j / RT) & 3;
        const float* up = uxyz + (size_t)r * 3;
        float ux = up[0], uy = up[1], uz = up[2];
        u64 a0 = ~0ull, a1 = ~0ull, a2 = ~0ull;
        for (int k = lane; k < M; k += 64) {
            float d = d2rn(kxs[k * 3], kxs[k * 3 + 1], kxs[k * 3 + 2], ux, uy, uz);
            u64 key = ((u64)__float_as_uint(d) << 32) | (unsigned)k;
            if (key < a0)      { a2 = a1; a1 = a0; a0 = key; }
            else if (key < a1) { a2 = a1; a1 = key; }
            else if (key < a2) { a2 = key; }
        }
#pragma unroll
        for (int m = 1; m < 64; m <<= 1) {   // merge sorted triples (exact order stats)
            u64 b0k = shfl_xor_u64(a0, m), b1k = shfl_xor_u64(a1, m), b2k = shfl_xor_u64(a2, m);
            u64 c0 = umin64(a0, b0k);
            u64 c1 = umin64(umax64(a0, b0k), umin64(a1, b1k));
            u64 c2 = umin64(umin64(umax64(a1, b0k), umax64(a0, b1k)), umin64(a2, b2k));
            a0 = c0; a1 = c1; a2 = c2;
        }
        int s0 = (int)(unsigned)a0, s1 = (int)(unsigned)a1, s2 = (int)(unsigned)a2;
        float d0 = __uint_as_float((unsigned)(a0 >> 32));
        float d1 = __uint_as_float((unsigned)(a1 >> 32));
        float dd2 = __uint_as_float((unsigned)(a2 >> 32));
        float wa = 1.0f / (d0 + 1e-8f), wb = 1.0f / (d1 + 1e-8f), wc = 1.0f / (dd2 + 1e-8f);
        float sum = (wa + wb) + wc;
        wa /= sum; wb /= sum; wc /= sum;
        const float* kb = kfeat + (size_t)b * M * CK;
        for (int c4 = lane; c4 < CK / 4; c4 += 64) {
            float4 va = *(const float4*)(kb + (size_t)s0 * CK + c4 * 4);
            float4 vb = *(const float4*)(kb + (size_t)s1 * CK + c4 * 4);
            float4 vc = *(const float4*)(kb + (size_t)s2 * CK + c4 * 4);
            float4 rr;
            rr.x = va.x * wa + vb.x * wb + vc.x * wc;
            rr.y = va.y * wa + vb.y * wb + vc.y * wc;
            rr.z = va.z * wa + vb.z * wb + vc.z * wc;
            rr.w = va.w * wa + vb.w * wb + vc.w * wc;
            *(float4*)&Xs[(j * XSTR4 + (c4 ^ sw)) * 4] = rr;
        }
        for (int c = CK + lane; c < CH; c += 64)
            Xs[(j * XSTR4 + ((c >> 2) ^ sw)) * 4 + (c & 3)] =
                ufeat[(size_t)r * CU + (c - CK)];
        for (int c = CH + lane; c < CI16A; c += 64)
            Xs[(j * XSTR4 + ((c >> 2) ^ sw)) * 4 + (c & 3)] = 0.f;
    }
    gemm_phase<TR, XSTR, CH, C1, 0>(Xs, Ws, w0, g0, b0, nullptr, nullptr, 0, nullptr, t);
    gemm_phase<TR, XSTR, C1, C2, 0>(Xs, Ws, w1, g1, b1, nullptr, nullptr, 0, nullptr, t);
    if constexpr (FINAL) {
        gemm_phase<TR, XSTR, C2, 512, 1>(Xs, Ws, fw, fg, fbe, fb, out, r0, nullptr, t);
    } else {
        for (int e = t; e < TR * C2; e += 256) {
            int j = e / C2, c = e % C2;
            int sw = (j / RT) & 3;
            out[(size_t)(r0 + j) * C2 + c] = Xs[(j * XSTR4 + ((c >> 2) ^ sw)) * 4 + (c & 3)];
        }
    }
}

extern "C" void kernel_launch(void* const* d_in, const int* in_sizes, int n_in,
                              void* d_out, int out_size, void* d_ws, size_t ws_size,
                              hipStream_t stream) {
    (void)in_sizes; (void)n_in; (void)out_size; (void)ws_size;
    const float* xyz   = (const float*)d_in[0];
    const float* feats = (const float*)d_in[1];  // [B,N,3] point-major
    const float* sa1_w0 = (const float*)d_in[2];
    const float* sa1_g0 = (const float*)d_in[3];
    const float* sa1_b0 = (const float*)d_in[4];
    const float* sa1_w1 = (const float*)d_in[5];
    const float* sa1_g1 = (const float*)d_in[6];
    const float* sa1_b1 = (const float*)d_in[7];
    const float* sa2_w0 = (const float*)d_in[8];
    const float* sa2_g0 = (const float*)d_in[9];
    const float* sa2_b0 = (const float*)d_in[10];
    const float* sa2_w1 = (const float*)d_in[11];
    const float* sa2_g1 = (const float*)d_in[12];
    const float* sa2_b1 = (const float*)d_in[13];
    const float* sa3_w0 = (const float*)d_in[14];
    const float* sa3_g0 = (const float*)d_in[15];
    const float* sa3_b0 = (const float*)d_in[16];
    const float* sa3_w1 = (const float*)d_in[17];
    const float* sa3_g1 = (const float*)d_in[18];
    const float* sa3_b1 = (const float*)d_in[19];
    const float* fp3_w0 = (const float*)d_in[20];
    const float* fp3_g0 = (const float*)d_in[21];
    const float* fp3_b0 = (const float*)d_in[22];
    const float* fp3_w1 = (const float*)d_in[23];
    const float* fp3_g1 = (const float*)d_in[24];
    const float* fp3_b1 = (const float*)d_in[25];
    const float* fp2_w0 = (const float*)d_in[26];
    const float* fp2_g0 = (const float*)d_in[27];
    const float* fp2_b0 = (const float*)d_in[28];
    const float* fp2_w1 = (const float*)d_in[29];
    const float* fp2_g1 = (const float*)d_in[30];
    const float* fp2_b1 = (const float*)d_in[31];
    const float* fp1_w0 = (const float*)d_in[32];
    const float* fp1_g0 = (const float*)d_in[33];
    const float* fp1_b0 = (const float*)d_in[34];
    const float* fp1_w1 = (const float*)d_in[35];
    const float* fp1_g1 = (const float*)d_in[36];
    const float* fp1_b1 = (const float*)d_in[37];
    const float* fin_w  = (const float*)d_in[38];
    const float* fin_b  = (const float*)d_in[39];
    const float* fin_g  = (const float*)d_in[40];
    const float* fin_be = (const float*)d_in[41];

    float* ws = (float*)d_ws;
    float* l1x  = ws;                 // 16*256*3    = 12288
    float* l1f  = l1x + 12288;        // 16*256*128  = 524288
    float* l2x  = l1f + 524288;       // 16*64*3     = 3072
    float* l2f  = l2x + 3072;         // 16*64*256   = 262144
    float* l3x  = l2f + 262144;       // 16*16*3     = 768
    float* l3f  = l3x + 768;          // 16*16*512   = 131072
    float* l2fb = l3f + 131072;       // 16*64*256   = 262144
    float* l1fb = l2fb + 262144;      // 16*256*128  = 524288
    int* fidx1 = (int*)(l1fb + 524288);  // 16*256
    int* fidx2 = fidx1 + 4096;           // 16*64
    int* fidx3 = fidx2 + 1024;           // 16*16

    const float R2_1 = (float)(0.04 * 0.04);
    const float R2_2 = (float)(0.08 * 0.08);
    const float R2_3 = (float)(0.16 * 0.16);

    fps_kernel<4096, 256, 512><<<16, 512, 0, stream>>>(xyz, fidx1);
    sa_kernel<4096, 256, 3, 64, 128, 64><<<16 * 256 / 4, 256, 0, stream>>>(
        xyz, feats, fidx1, sa1_w0, sa1_g0, sa1_b0, sa1_w1, sa1_g1, sa1_b1,
        l1x, l1f, R2_1);

    fps_kernel<256, 64, 256><<<16, 256, 0, stream>>>(l1x, fidx2);
    sa_kernel<256, 64, 128, 128, 256, 32><<<16 * 64 / 2, 256, 0, stream>>>(
        l1x, l1f, fidx2, sa2_w0, sa2_g0, sa2_b0, sa2_w1, sa2_g1, sa2_b1,
        l2x, l2f, R2_2);

    fps_kernel<64, 16, 64><<<16, 64, 0, stream>>>(l2x, fidx3);
    sa_kernel<64, 16, 256, 256, 512, 16><<<16 * 16, 256, 0, stream>>>(
        l2x, l2f, fidx3, sa3_w0, sa3_g0, sa3_b0, sa3_w1, sa3_g1, sa3_b1,
        l3x, l3f, R2_3);

    // FP3: unk=l2 (1024 rows), kn=l3 (M=16), 768 -> 256 -> 256
    fp_kernel<16, 512, 256, 256, 256, 16, false><<<1024 / 16, 256, 0, stream>>>(
        l2x, l3x, l2f, l3f, fp3_w0, fp3_g0, fp3_b0, fp3_w1, fp3_g1, fp3_b1,
        nullptr, nullptr, nullptr, nullptr, l2fb, 64);

    // FP2: unk=l1 (4096 rows), kn=l2 (M=64), 384 -> 128 -> 128
    fp_kernel<64, 256, 128, 128, 128, 16, false><<<4096 / 16, 256, 0, stream>>>(
        l1x, l2x, l1f, l2fb, fp2_w0, fp2_g0, fp2_b0, fp2_w1, fp2_g1, fp2_b1,
        nullptr, nullptr, nullptr, nullptr, l1fb, 256);

    // FP1: unk=xyz (65536 rows), kn=l1 (M=256), 131 -> 128 -> 128, fused 128->512
    fp_kernel<256, 128, 3, 128, 128, 64, true><<<65536 / 64, 256, 0, stream>>>(
        xyz, l1x, feats, l1fb, fp1_w0, fp1_g0, fp1_b0, fp1_w1, fp1_g1, fp1_b1,
        fin_w, fin_b, fin_g, fin_be, (float*)d_out, 4096);
}